// Round 5
// baseline (984.685 us; speedup 1.0000x reference)
//
#include <hip/hip_runtime.h>

// K-means (8 clusters, 10 iters) on 64 batches of 512*512 RGB pixels,
// bit-exact jax.random init (partitionable threefry, xor-fold bits,
// 2-round stable-sort permutation). Correctness locked since round 2.
//
// Round-5 (perf):
//  - k1 split into k1_h (bits1: store + LDS hist) and k1_c (bits2: capture),
//    each with explicit 2-way ILP threefry interleave (probe for the
//    38%-VALUBusy stall: serial dependent chains not interleaved by compiler).
//  - Pixels quantized once to u16 fixed-point (error 2^-17): assign iter 0
//    reads exact f32 and fuses the pack-store; iters 1-9 read 96 MB packed
//    (L3-resident) instead of 192 MB f32. Accumulation in u-space (exact
//    x*2^16 scaling), means rescaled by 2^-16 in phase A / kfinal.
//  - bits1 (dead after k3a) unions with packed array; ws_size runtime check
//    falls back to all-f32 assigns if workspace too small.

#define NBATCH 64
#define NPIX   262144   // 512*512 = 2^18
#define NCLUST 8
#define NITER  10
#define NBIN   1024
#define CAP2   1024
#define CAP1   512
#define THRESH2 (1u << 23)
#define IDXMASK 0x3FFFFull
#define NCHUNK 16       // assign blocks per batch
#define USCALE 65536.0f
#define UINV   (1.0f / 65536.0f)

struct WS {
  unsigned long long list2[NBATCH][CAP2];
  unsigned long long list1[NBATCH][NCLUST][CAP1];
  unsigned int subkeys[NBATCH][4];
  unsigned int hist[NBATCH][NBIN];
  unsigned int cnt2[NBATCH];
  unsigned int cnt1[NBATCH][NCLUST];
  unsigned int binr[NBATCH][NCLUST][2];
  float cent[NITER][NBATCH][NCLUST][3];          // real-space centroids
  float partial[2][NBATCH][NCHUNK][NCLUST][4];   // u-space sums + count
  union {                                        // LAST member; aliased:
    unsigned int   bits1[NBATCH][NPIX];          //  used k1_h..k3a   (64 MB)
    unsigned short packed[(size_t)NBATCH * NPIX * 3];  // used assign0+ (101 MB)
  } u;
};

__device__ __forceinline__ unsigned int rotl32(unsigned int x, int d) {
  return __builtin_amdgcn_alignbit(x, x, (unsigned int)(32 - d));
}

__device__ __forceinline__ void threefry2x32(unsigned int k0, unsigned int k1,
                                             unsigned int x0, unsigned int x1,
                                             unsigned int &y0, unsigned int &y1) {
  const unsigned int ks2 = k0 ^ k1 ^ 0x1BD11BDAu;
  x0 += k0; x1 += k1;
#define TF_ROUND(r) { x0 += x1; x1 = rotl32(x1, r); x1 ^= x0; }
  TF_ROUND(13) TF_ROUND(15) TF_ROUND(26) TF_ROUND(6)
  x0 += k1;  x1 += ks2 + 1u;
  TF_ROUND(17) TF_ROUND(29) TF_ROUND(16) TF_ROUND(24)
  x0 += ks2; x1 += k0 + 2u;
  TF_ROUND(13) TF_ROUND(15) TF_ROUND(26) TF_ROUND(6)
  x0 += k0;  x1 += k1 + 3u;
  TF_ROUND(17) TF_ROUND(29) TF_ROUND(16) TF_ROUND(24)
  x0 += k1;  x1 += ks2 + 4u;
  TF_ROUND(13) TF_ROUND(15) TF_ROUND(26) TF_ROUND(6)
  x0 += ks2; x1 += k0 + 5u;
#undef TF_ROUND
  y0 = x0; y1 = x1;
}

// two interleaved threefry states (forced ILP-2)
__device__ __forceinline__ void threefry2x32_x2(unsigned int k0, unsigned int k1,
                                                unsigned int ia, unsigned int ib,
                                                unsigned int &ra, unsigned int &rb) {
  const unsigned int ks2 = k0 ^ k1 ^ 0x1BD11BDAu;
  unsigned int a0 = k0, a1 = ia + k1;
  unsigned int b0 = k0, b1 = ib + k1;
#define TF_R2(r) { a0 += a1; b0 += b1; \
                   a1 = rotl32(a1, r); b1 = rotl32(b1, r); \
                   a1 ^= a0; b1 ^= b0; }
#define TF_K2(ka, kb, n) { a0 += ka; b0 += ka; a1 += kb + n; b1 += kb + n; }
  TF_R2(13) TF_R2(15) TF_R2(26) TF_R2(6)  TF_K2(k1, ks2, 1u)
  TF_R2(17) TF_R2(29) TF_R2(16) TF_R2(24) TF_K2(ks2, k0, 2u)
  TF_R2(13) TF_R2(15) TF_R2(26) TF_R2(6)  TF_K2(k0, k1, 3u)
  TF_R2(17) TF_R2(29) TF_R2(16) TF_R2(24) TF_K2(k1, ks2, 4u)
  TF_R2(13) TF_R2(15) TF_R2(26) TF_R2(6)  TF_K2(ks2, k0, 5u)
#undef TF_R2
#undef TF_K2
  ra = a0 ^ a1;
  rb = b0 ^ b1;
}

__device__ __forceinline__ unsigned long long umin64(unsigned long long a,
                                                     unsigned long long b) {
  return a < b ? a : b;
}

// ---------------------------------------------------------------- K0: setup
__global__ __launch_bounds__(256) void k0_setup(const float* __restrict__ in,
                                                WS* __restrict__ ws) {
  const int b = blockIdx.x, t = threadIdx.x;
  for (int i = t; i < NBIN; i += 256) ws->hist[b][i] = 0u;
  if (t < NCLUST) {
    ws->cnt1[b][t] = 0u;
    const float* p = in + ((size_t)b * NPIX + (size_t)t) * 3;  // fallback init
    ws->cent[0][b][t][0] = p[0];
    ws->cent[0][b][t][1] = p[1];
    ws->cent[0][b][t][2] = p[2];
  }
  if (t == 0) {
    ws->cnt2[b] = 0u;
    unsigned int kb0, kb1, ka0, ka1, u0, u1;
    threefry2x32(0u, 42u, 0u, (unsigned int)b, kb0, kb1);  // batch key
    threefry2x32(kb0, kb1, 0u, 0u, ka0, ka1);              // carried key
    threefry2x32(kb0, kb1, 0u, 1u, u0, u1);                // round-1 subkey
    ws->subkeys[b][0] = u0; ws->subkeys[b][1] = u1;
    threefry2x32(ka0, ka1, 0u, 1u, u0, u1);                // round-2 subkey
    ws->subkeys[b][2] = u0; ws->subkeys[b][3] = u1;
  }
}

// ------------------- K1_h: bits1 stream -> store + LDS histogram (ILP-2)
__global__ __launch_bounds__(256) void k1_h(WS* __restrict__ ws) {
  const int b = blockIdx.x >> 5, chunk = blockIdx.x & 31, t = threadIdx.x;
  __shared__ unsigned int lhist[NBIN];
  for (int i = t; i < NBIN; i += 256) lhist[i] = 0u;
  __syncthreads();
  const unsigned int k0 = ws->subkeys[b][0], k1 = ws->subkeys[b][1];
  const unsigned int i0 = (unsigned int)chunk * 8192u + (unsigned int)t;
  unsigned int* __restrict__ bout = &ws->u.bits1[b][0];
#pragma unroll 1
  for (int j = 0; j < 16; ++j) {
    const unsigned int ia = i0 + (unsigned int)(j * 512);
    const unsigned int ib = ia + 256u;
    unsigned int ra, rb;
    threefry2x32_x2(k0, k1, ia, ib, ra, rb);
    bout[ia] = ra;
    bout[ib] = rb;
    atomicAdd(&lhist[ra >> 22], 1u);
    atomicAdd(&lhist[rb >> 22], 1u);
  }
  __syncthreads();
  for (int i = t; i < NBIN; i += 256)
    if (lhist[i]) atomicAdd(&ws->hist[b][i], lhist[i]);
}

// ------------------- K1_c: bits2 stream -> candidate capture (ILP-2)
__global__ __launch_bounds__(256) void k1_c(WS* __restrict__ ws) {
  const int b = blockIdx.x >> 5, chunk = blockIdx.x & 31, t = threadIdx.x;
  const unsigned int k0 = ws->subkeys[b][2], k1 = ws->subkeys[b][3];
  const unsigned int i0 = (unsigned int)chunk * 8192u + (unsigned int)t;
#pragma unroll 1
  for (int j = 0; j < 16; ++j) {
    const unsigned int ia = i0 + (unsigned int)(j * 512);
    const unsigned int ib = ia + 256u;
    unsigned int ra, rb;
    threefry2x32_x2(k0, k1, ia, ib, ra, rb);
    if (ra < THRESH2) {
      const unsigned int pos = atomicAdd(&ws->cnt2[b], 1u);
      if (pos < CAP2)
        ws->list2[b][pos] = ((unsigned long long)ra << 18) | (unsigned long long)ia;
    }
    if (rb < THRESH2) {
      const unsigned int pos = atomicAdd(&ws->cnt2[b], 1u);
      if (pos < CAP2)
        ws->list2[b][pos] = ((unsigned long long)rb << 18) | (unsigned long long)ib;
    }
  }
}

// -------------------------- K2: top-8 of round-2; map ranks -> (bin, residual)
__global__ __launch_bounds__(256) void k2_select(WS* __restrict__ ws) {
  const int b = blockIdx.x, t = threadIdx.x;
  const int lane = t & 63, wv = t >> 6;
  __shared__ unsigned long long lc[CAP2];
  __shared__ unsigned long long wmin[4];
  __shared__ unsigned int lbins[NBIN + 1];
  __shared__ unsigned int lq[NCLUST];
  __shared__ unsigned int psum[256];
  const unsigned int c2 = ws->cnt2[b];
  const int m2 = (int)(c2 < CAP2 ? c2 : CAP2);
  for (int e = t; e < m2; e += 256) lc[e] = ws->list2[b][e];
  __syncthreads();
  for (int j = 0; j < NCLUST; ++j) {
    unsigned long long lm = ~0ull;
    for (int e = t; e < m2; e += 256) lm = umin64(lm, lc[e]);
#pragma unroll
    for (int off = 32; off > 0; off >>= 1)
      lm = umin64(lm, __shfl_down(lm, off, 64));
    if (lane == 0) wmin[wv] = lm;
    __syncthreads();
    if (t == 0) {
      const unsigned long long M =
          umin64(umin64(wmin[0], wmin[1]), umin64(wmin[2], wmin[3]));
      wmin[0] = M;
      lq[j] = (unsigned int)(M & IDXMASK);
    }
    __syncthreads();
    const unsigned long long M = wmin[0];
    for (int e = t; e < m2; e += 256)
      if (lc[e] == M) lc[e] = ~0ull;
    __syncthreads();
  }
  unsigned int h[4];
  unsigned int s = 0;
  {
    const int base = t * 4;
#pragma unroll
    for (int r = 0; r < 4; ++r) { h[r] = ws->hist[b][base + r]; s += h[r]; }
    psum[t] = s;
  }
  __syncthreads();
  for (int st = 1; st < 256; st <<= 1) {
    unsigned int v = 0;
    if (t >= st) v = psum[t - st];
    __syncthreads();
    psum[t] += v;
    __syncthreads();
  }
  {
    unsigned int run = psum[t] - s;
    const int base = t * 4;
#pragma unroll
    for (int r = 0; r < 4; ++r) { lbins[base + r] = run; run += h[r]; }
    if (t == 255) lbins[NBIN] = run;
  }
  __syncthreads();
  {
    const int base = t * 4;
#pragma unroll
    for (int r = 0; r < 4; ++r) {
      const unsigned int lo = lbins[base + r], hi = lbins[base + r + 1];
      for (int j = 0; j < NCLUST; ++j) {
        const unsigned int q = lq[j];
        if (q >= lo && q < hi) {
          ws->binr[b][j][0] = (unsigned int)(base + r);
          ws->binr[b][j][1] = q - lo;
        }
      }
    }
  }
}

// ------------------ K3a: capture bin candidates from stored bits1 (mem-bound)
__global__ __launch_bounds__(256) void k3a_read(WS* __restrict__ ws) {
  const int b = blockIdx.x >> 5, chunk = blockIdx.x & 31, t = threadIdx.x;
  unsigned int bins[NCLUST];
#pragma unroll
  for (int j = 0; j < NCLUST; ++j) bins[j] = ws->binr[b][j][0];
  const unsigned int i0 = (unsigned int)chunk * 8192u;
  const uint4* __restrict__ p = (const uint4*)&ws->u.bits1[b][i0];
#pragma unroll 1
  for (int jj = 0; jj < 8; ++jj) {
    const uint4 v = p[jj * 256 + t];
    const unsigned int iv[4] = {v.x, v.y, v.z, v.w};
#pragma unroll
    for (int c = 0; c < 4; ++c) {
      const unsigned int bits1 = iv[c];
      const unsigned int i = i0 + (unsigned int)((jj * 256 + t) * 4 + c);
      const unsigned int bin = bits1 >> 22;
      const unsigned long long comp =
          ((unsigned long long)bits1 << 18) | (unsigned long long)i;
#pragma unroll
      for (int j = 0; j < NCLUST; ++j) {
        if (bin == bins[j]) {
          const unsigned int pos = atomicAdd(&ws->cnt1[b][j], 1u);
          if (pos < CAP1) ws->list1[b][j][pos] = comp;
        }
      }
    }
  }
}

// ------------------- K4: in-bin rank selection -> init centroid gather
__global__ __launch_bounds__(256) void k4_pick(const float* __restrict__ in,
                                               WS* __restrict__ ws) {
  const int b = blockIdx.x >> 3, j = blockIdx.x & 7, t = threadIdx.x;
  __shared__ unsigned long long l1[CAP1];
  const unsigned int c1 = ws->cnt1[b][j];
  const int m = (int)(c1 < CAP1 ? c1 : CAP1);
  const unsigned int r = ws->binr[b][j][1];
  for (int e = t; e < m; e += 256) l1[e] = ws->list1[b][j][e];
  __syncthreads();
  for (int e = t; e < m; e += 256) {
    const unsigned long long v = l1[e];
    unsigned int rank = 0;
    for (int f = 0; f < m; ++f) rank += (l1[f] < v) ? 1u : 0u;
    if (rank == r) {
      const unsigned int i = (unsigned int)(v & IDXMASK);
      const float* p = in + ((size_t)b * NPIX + i) * 3;
      ws->cent[0][b][j][0] = p[0];
      ws->cent[0][b][j][1] = p[1];
      ws->cent[0][b][j][2] = p[2];
    }
  }
}

// --------- assign. MODE 0: read f32 + pack-store u16 (iter 0, big ws)
//           MODE 1: read packed u16 (iters 1.., big ws)
//           MODE 2: read f32, no pack (all iters, small-ws fallback)
// All modes accumulate in u-space (x * 2^16; exact for MODE 0/2).
template <int MODE>
__global__ __launch_bounds__(256) void kmeans_assign(const float* __restrict__ in,
                                                     WS* __restrict__ ws,
                                                     int iter) {
  const int b = blockIdx.x >> 4, chunk = blockIdx.x & 15, t = threadIdx.x;
  __shared__ float scent[NCLUST][3];
  __shared__ float sred[4][NCLUST][4];

  // ---- phase A: this iteration's centroids (real space)
  if (iter == 0) {
    if (t < NCLUST * 3) (&scent[0][0])[t] = (&ws->cent[0][b][0][0])[t];
  } else {
    const int pb = (iter - 1) & 1;
    if (t < 32) {
      const int k = t >> 2, c = t & 3;
      float s = 0.f;
#pragma unroll
      for (int ch = 0; ch < NCHUNK; ++ch) s += ws->partial[pb][b][ch][k][c];
      sred[0][k][c] = s;
    }
    __syncthreads();
    if (t < NCLUST) {
      const int k = t;
      const float cnt = sred[0][k][3];
      const float denom = fmaxf(cnt, 1.f);
      float nx, ny, nz;
      if (cnt > 0.f) {
        nx = (sred[0][k][0] / denom) * UINV;   // u-space sum -> real mean
        ny = (sred[0][k][1] / denom) * UINV;
        nz = (sred[0][k][2] / denom) * UINV;
      } else {
        nx = ws->cent[iter - 1][b][k][0];
        ny = ws->cent[iter - 1][b][k][1];
        nz = ws->cent[iter - 1][b][k][2];
      }
      scent[k][0] = nx; scent[k][1] = ny; scent[k][2] = nz;
      ws->cent[iter][b][k][0] = nx;
      ws->cent[iter][b][k][1] = ny;
      ws->cent[iter][b][k][2] = nz;
    }
  }
  __syncthreads();

  // distance coefficients: MODE 1 works in u-space, MODE 0/2 in real space
  float ca[NCLUST], cb[NCLUST], cc[NCLUST], cd[NCLUST];
#pragma unroll
  for (int k = 0; k < NCLUST; ++k) {
    const float sc = (MODE == 1) ? USCALE : 1.f;
    const float x = scent[k][0] * sc, y = scent[k][1] * sc, z = scent[k][2] * sc;
    ca[k] = -2.f * x; cb[k] = -2.f * y; cc[k] = -2.f * z;
    cd[k] = fmaf(x, x, fmaf(y, y, z * z));
  }
  float ax[NCLUST], ay[NCLUST], az[NCLUST], an[NCLUST];
#pragma unroll
  for (int k = 0; k < NCLUST; ++k) { ax[k] = 0.f; ay[k] = 0.f; az[k] = 0.f; an[k] = 0.f; }

  const size_t pixbase = (size_t)b * NPIX + (size_t)chunk * 16384;

  if (MODE == 1) {
    // ---- packed path: 8 px / thread-iter via 3x uint4
    const uint4* __restrict__ pp =
        (const uint4*)(ws->u.packed + pixbase * 3);
#pragma unroll 2
    for (int jj = 0; jj < 8; ++jj) {
      const int g = jj * 256 + t;          // 8-pixel group
      const uint4 w0 = pp[g * 3], w1 = pp[g * 3 + 1], w2 = pp[g * 3 + 2];
      const unsigned int wrd[12] = {w0.x, w0.y, w0.z, w0.w, w1.x, w1.y,
                                    w1.z, w1.w, w2.x, w2.y, w2.z, w2.w};
#pragma unroll
      for (int p = 0; p < 8; ++p) {
        const int f = p * 3;
        const unsigned int c0 = (f & 1) ? (wrd[f >> 1] >> 16) : (wrd[f >> 1] & 0xFFFFu);
        const unsigned int c1 = ((f + 1) & 1) ? (wrd[(f + 1) >> 1] >> 16) : (wrd[(f + 1) >> 1] & 0xFFFFu);
        const unsigned int c2 = ((f + 2) & 1) ? (wrd[(f + 2) >> 1] >> 16) : (wrd[(f + 2) >> 1] & 0xFFFFu);
        const float x = (float)c0, y = (float)c1, z = (float)c2;
        float bv = fmaf(ca[0], x, fmaf(cb[0], y, fmaf(cc[0], z, cd[0])));
        int bk = 0;
#pragma unroll
        for (int k = 1; k < NCLUST; ++k) {
          const float tk = fmaf(ca[k], x, fmaf(cb[k], y, fmaf(cc[k], z, cd[k])));
          if (tk < bv) { bv = tk; bk = k; }
        }
#pragma unroll
        for (int k = 0; k < NCLUST; ++k) {
          const float w = (bk == k) ? 1.f : 0.f;
          ax[k] = fmaf(w, x, ax[k]);
          ay[k] = fmaf(w, y, ay[k]);
          az[k] = fmaf(w, z, az[k]);
          an[k] += w;
        }
      }
    }
  } else {
    // ---- f32 path: 4 px / thread-iter via 3x float4 (+ optional pack store)
    const float4* __restrict__ in4 = (const float4*)(in + pixbase * 3);
    uint2* __restrict__ pk =
        (MODE == 0) ? (uint2*)(ws->u.packed + pixbase * 3) : (uint2*)0;
#pragma unroll 4
    for (int jj = 0; jj < 16; ++jj) {
      const int g = jj * 256 + t;          // 4-pixel group
      const int fb = g * 3;
      const float4 v0 = in4[fb], v1 = in4[fb + 1], v2 = in4[fb + 2];
      float pxv[12];
      pxv[0] = v0.x;  pxv[1] = v0.y;  pxv[2]  = v0.z;  pxv[3]  = v0.w;
      pxv[4] = v1.x;  pxv[5] = v1.y;  pxv[6]  = v1.z;  pxv[7]  = v1.w;
      pxv[8] = v2.x;  pxv[9] = v2.y;  pxv[10] = v2.z;  pxv[11] = v2.w;
      if (MODE == 0) {
        unsigned int uq[12];
#pragma unroll
        for (int c = 0; c < 12; ++c) {
          unsigned int u = (unsigned int)fmaf(pxv[c], USCALE, 0.5f);
          uq[c] = u > 65535u ? 65535u : u;
        }
        pk[fb]     = make_uint2(uq[0] | (uq[1] << 16), uq[2] | (uq[3] << 16));
        pk[fb + 1] = make_uint2(uq[4] | (uq[5] << 16), uq[6] | (uq[7] << 16));
        pk[fb + 2] = make_uint2(uq[8] | (uq[9] << 16), uq[10] | (uq[11] << 16));
      }
#pragma unroll
      for (int p = 0; p < 4; ++p) {
        const float x = pxv[p * 3], y = pxv[p * 3 + 1], z = pxv[p * 3 + 2];
        float bv = fmaf(ca[0], x, fmaf(cb[0], y, fmaf(cc[0], z, cd[0])));
        int bk = 0;
#pragma unroll
        for (int k = 1; k < NCLUST; ++k) {
          const float tk = fmaf(ca[k], x, fmaf(cb[k], y, fmaf(cc[k], z, cd[k])));
          if (tk < bv) { bv = tk; bk = k; }
        }
        const float xs = x * USCALE, ys = y * USCALE, zs = z * USCALE;  // exact
#pragma unroll
        for (int k = 0; k < NCLUST; ++k) {
          const float w = (bk == k) ? 1.f : 0.f;
          ax[k] = fmaf(w, xs, ax[k]);
          ay[k] = fmaf(w, ys, ay[k]);
          az[k] = fmaf(w, zs, az[k]);
          an[k] += w;
        }
      }
    }
  }

  // ---- block reduction -> private partial slot (u-space)
  const int lane = t & 63, wv = t >> 6;
#pragma unroll
  for (int k = 0; k < NCLUST; ++k) {
    float vx = ax[k], vy = ay[k], vz = az[k], vn = an[k];
#pragma unroll
    for (int off = 32; off > 0; off >>= 1) {
      vx += __shfl_down(vx, off, 64);
      vy += __shfl_down(vy, off, 64);
      vz += __shfl_down(vz, off, 64);
      vn += __shfl_down(vn, off, 64);
    }
    if (lane == 0) {
      sred[wv][k][0] = vx; sred[wv][k][1] = vy;
      sred[wv][k][2] = vz; sred[wv][k][3] = vn;
    }
  }
  __syncthreads();
  if (t < 32) {
    const int k = t >> 2, c = t & 3;
    const float p = sred[0][k][c] + sred[1][k][c] + sred[2][k][c] + sred[3][k][c];
    ws->partial[iter & 1][b][chunk][k][c] = p;
  }
}

// ----------------------- final: C_10 from iter-9 partials -> output
__global__ __launch_bounds__(64) void kfinal(WS* __restrict__ ws,
                                             float* __restrict__ out) {
  const int b = blockIdx.x, t = threadIdx.x;
  __shared__ float s[NCLUST][4];
  if (t < 32) {
    const int k = t >> 2, c = t & 3;
    float v = 0.f;
#pragma unroll
    for (int ch = 0; ch < NCHUNK; ++ch)
      v += ws->partial[(NITER - 1) & 1][b][ch][k][c];
    s[k][c] = v;
  }
  __syncthreads();
  if (t < NCLUST) {
    const int k = t;
    const float cnt = s[k][3];
    const float denom = fmaxf(cnt, 1.f);
    float nx, ny, nz;
    if (cnt > 0.f) {
      nx = (s[k][0] / denom) * UINV;
      ny = (s[k][1] / denom) * UINV;
      nz = (s[k][2] / denom) * UINV;
    } else {
      nx = ws->cent[NITER - 1][b][k][0];
      ny = ws->cent[NITER - 1][b][k][1];
      nz = ws->cent[NITER - 1][b][k][2];
    }
    const int o = (b * NCLUST + k) * 3;
    out[o + 0] = nx; out[o + 1] = ny; out[o + 2] = nz;
  }
}

extern "C" void kernel_launch(void* const* d_in, const int* in_sizes, int n_in,
                              void* d_out, int out_size, void* d_ws, size_t ws_size,
                              hipStream_t stream) {
  const float* in = (const float*)d_in[0];
  float* out = (float*)d_out;
  WS* ws = (WS*)d_ws;   // ~104 MB if packed path; union tail only needs 64 MB otherwise
  const size_t need_full = sizeof(WS);
  const bool packed_ok = ws_size >= need_full;   // deterministic: graph-safe

  k0_setup<<<NBATCH, 256, 0, stream>>>(in, ws);
  k1_h<<<NBATCH * 32, 256, 0, stream>>>(ws);
  k1_c<<<NBATCH * 32, 256, 0, stream>>>(ws);
  k2_select<<<NBATCH, 256, 0, stream>>>(ws);
  k3a_read<<<NBATCH * 32, 256, 0, stream>>>(ws);
  k4_pick<<<NBATCH * NCLUST, 256, 0, stream>>>(in, ws);
  if (packed_ok) {
    kmeans_assign<0><<<NBATCH * NCHUNK, 256, 0, stream>>>(in, ws, 0);
    for (int it = 1; it < NITER; ++it)
      kmeans_assign<1><<<NBATCH * NCHUNK, 256, 0, stream>>>(in, ws, it);
  } else {
    for (int it = 0; it < NITER; ++it)
      kmeans_assign<2><<<NBATCH * NCHUNK, 256, 0, stream>>>(in, ws, it);
  }
  kfinal<<<NBATCH, 64, 0, stream>>>(ws, out);
}

// Round 6
// 794.878 us; speedup vs baseline: 1.2388x; 1.2388x over previous
//
#include <hip/hip_runtime.h>

// K-means (8 clusters, 10 iters) on 64 batches of 512*512 RGB pixels,
// bit-exact jax.random init (partitionable threefry, xor-fold bits,
// 2-round stable-sort permutation). Correctness locked since round 2.
//
// Round-6 (perf): ZERO return-atomics in the init chain.
//   Round-5 probe showed k1_c (capture only) = 168 us @ VALUBusy 22% with no
//   memory traffic: the stall is same-cache-line device-scope atomicAdd
//   returns (cnt2[64] in ~2 lines, 2048 blocks, cross-XCD line ping-pong),
//   NOT threefry ILP. Fix: per-block private capture segments + plain counts;
//   k2/k4 compact in LDS. Selection is min-over-composites => order-free,
//   init indices unchanged. k1_h/k1_c re-merged (one less GPU drain).

#define NBATCH 64
#define NPIX   262144   // 512*512 = 2^18
#define NCLUST 8
#define NITER  10
#define NBIN   1024
#define NSEG   32       // init blocks per batch
#define CAP2S  64       // per-chunk round-2 capture (lambda=16, +12 sigma)
#define CAP1S  32       // per-chunk-per-cluster round-1 capture (lambda=8)
#define THRESH2 (1u << 23)
#define IDXMASK 0x3FFFFull
#define NCHUNK 16       // assign blocks per batch
#define USCALE 65536.0f
#define UINV   (1.0f / 65536.0f)

struct WS {
  unsigned long long list2[NBATCH][NSEG][CAP2S];          // 1 MB
  unsigned long long list1[NBATCH][NSEG][NCLUST][CAP1S];  // 4 MB
  unsigned int cnt2c[NBATCH][NSEG];                       // plain writes
  unsigned int cnt1c[NBATCH][NSEG][NCLUST];               // plain writes
  unsigned int subkeys[NBATCH][4];
  unsigned int hist[NBATCH][NBIN];
  unsigned int binr[NBATCH][NCLUST][2];                   // bin, intra-bin rank
  float cent[NITER][NBATCH][NCLUST][3];                   // real-space centroids
  float partial[2][NBATCH][NCHUNK][NCLUST][4];            // u-space sums+count
  union {
    unsigned int   bits1[NBATCH][NPIX];                   // k1..k3a (64 MB)
    unsigned short packed[(size_t)NBATCH * NPIX * 3];     // assign (101 MB)
  } u;
};

__device__ __forceinline__ unsigned int rotl32(unsigned int x, int d) {
  return __builtin_amdgcn_alignbit(x, x, (unsigned int)(32 - d));
}

__device__ __forceinline__ void threefry2x32(unsigned int k0, unsigned int k1,
                                             unsigned int x0, unsigned int x1,
                                             unsigned int &y0, unsigned int &y1) {
  const unsigned int ks2 = k0 ^ k1 ^ 0x1BD11BDAu;
  x0 += k0; x1 += k1;
#define TF_ROUND(r) { x0 += x1; x1 = rotl32(x1, r); x1 ^= x0; }
  TF_ROUND(13) TF_ROUND(15) TF_ROUND(26) TF_ROUND(6)
  x0 += k1;  x1 += ks2 + 1u;
  TF_ROUND(17) TF_ROUND(29) TF_ROUND(16) TF_ROUND(24)
  x0 += ks2; x1 += k0 + 2u;
  TF_ROUND(13) TF_ROUND(15) TF_ROUND(26) TF_ROUND(6)
  x0 += k0;  x1 += k1 + 3u;
  TF_ROUND(17) TF_ROUND(29) TF_ROUND(16) TF_ROUND(24)
  x0 += k1;  x1 += ks2 + 4u;
  TF_ROUND(13) TF_ROUND(15) TF_ROUND(26) TF_ROUND(6)
  x0 += ks2; x1 += k0 + 5u;
#undef TF_ROUND
  y0 = x0; y1 = x1;
}

// two interleaved threefry states (xor-folded outputs)
__device__ __forceinline__ void threefry2x32_x2(unsigned int k0, unsigned int k1,
                                                unsigned int ia, unsigned int ib,
                                                unsigned int &ra, unsigned int &rb) {
  const unsigned int ks2 = k0 ^ k1 ^ 0x1BD11BDAu;
  unsigned int a0 = k0, a1 = ia + k1;
  unsigned int b0 = k0, b1 = ib + k1;
#define TF_R2(r) { a0 += a1; b0 += b1; \
                   a1 = rotl32(a1, r); b1 = rotl32(b1, r); \
                   a1 ^= a0; b1 ^= b0; }
#define TF_K2(ka, kb, n) { a0 += ka; b0 += ka; a1 += kb + n; b1 += kb + n; }
  TF_R2(13) TF_R2(15) TF_R2(26) TF_R2(6)  TF_K2(k1, ks2, 1u)
  TF_R2(17) TF_R2(29) TF_R2(16) TF_R2(24) TF_K2(ks2, k0, 2u)
  TF_R2(13) TF_R2(15) TF_R2(26) TF_R2(6)  TF_K2(k0, k1, 3u)
  TF_R2(17) TF_R2(29) TF_R2(16) TF_R2(24) TF_K2(k1, ks2, 4u)
  TF_R2(13) TF_R2(15) TF_R2(26) TF_R2(6)  TF_K2(ks2, k0, 5u)
#undef TF_R2
#undef TF_K2
  ra = a0 ^ a1;
  rb = b0 ^ b1;
}

__device__ __forceinline__ unsigned long long umin64(unsigned long long a,
                                                     unsigned long long b) {
  return a < b ? a : b;
}

// ---------------------------------------------------------------- K0: setup
__global__ __launch_bounds__(256) void k0_setup(const float* __restrict__ in,
                                                WS* __restrict__ ws) {
  const int b = blockIdx.x, t = threadIdx.x;
  for (int i = t; i < NBIN; i += 256) ws->hist[b][i] = 0u;
  if (t < NCLUST) {
    const float* p = in + ((size_t)b * NPIX + (size_t)t) * 3;  // fallback init
    ws->cent[0][b][t][0] = p[0];
    ws->cent[0][b][t][1] = p[1];
    ws->cent[0][b][t][2] = p[2];
  }
  if (t == 0) {
    unsigned int kb0, kb1, ka0, ka1, u0, u1;
    threefry2x32(0u, 42u, 0u, (unsigned int)b, kb0, kb1);  // batch key
    threefry2x32(kb0, kb1, 0u, 0u, ka0, ka1);              // carried key
    threefry2x32(kb0, kb1, 0u, 1u, u0, u1);                // round-1 subkey
    ws->subkeys[b][0] = u0; ws->subkeys[b][1] = u1;
    threefry2x32(ka0, ka1, 0u, 1u, u0, u1);                // round-2 subkey
    ws->subkeys[b][2] = u0; ws->subkeys[b][3] = u1;
  }
}

// ---- K1: bits1 (store + LDS hist) and bits2 (LDS capture -> private segment)
__global__ __launch_bounds__(256) void k1_scan(WS* __restrict__ ws) {
  const int b = blockIdx.x >> 5, chunk = blockIdx.x & 31, t = threadIdx.x;
  __shared__ unsigned int lhist[NBIN];
  __shared__ unsigned long long lcap[CAP2S];
  __shared__ unsigned int lcnt;
  for (int i = t; i < NBIN; i += 256) lhist[i] = 0u;
  if (t == 0) lcnt = 0u;
  __syncthreads();
  const unsigned int s1k0 = ws->subkeys[b][0], s1k1 = ws->subkeys[b][1];
  const unsigned int s2k0 = ws->subkeys[b][2], s2k1 = ws->subkeys[b][3];
  const unsigned int i0 = (unsigned int)chunk * 8192u + (unsigned int)t;
  unsigned int* __restrict__ bout = &ws->u.bits1[b][0];
#pragma unroll 1
  for (int j = 0; j < 16; ++j) {           // bits1 stream, ILP-2
    const unsigned int ia = i0 + (unsigned int)(j * 512);
    const unsigned int ib = ia + 256u;
    unsigned int ra, rb;
    threefry2x32_x2(s1k0, s1k1, ia, ib, ra, rb);
    bout[ia] = ra;
    bout[ib] = rb;
    atomicAdd(&lhist[ra >> 22], 1u);
    atomicAdd(&lhist[rb >> 22], 1u);
  }
#pragma unroll 1
  for (int j = 0; j < 16; ++j) {           // bits2 stream, ILP-2
    const unsigned int ia = i0 + (unsigned int)(j * 512);
    const unsigned int ib = ia + 256u;
    unsigned int ra, rb;
    threefry2x32_x2(s2k0, s2k1, ia, ib, ra, rb);
    if (ra < THRESH2) {
      const unsigned int pos = atomicAdd(&lcnt, 1u);   // LDS atomic only
      if (pos < CAP2S)
        lcap[pos] = ((unsigned long long)ra << 18) | (unsigned long long)ia;
    }
    if (rb < THRESH2) {
      const unsigned int pos = atomicAdd(&lcnt, 1u);
      if (pos < CAP2S)
        lcap[pos] = ((unsigned long long)rb << 18) | (unsigned long long)ib;
    }
  }
  __syncthreads();
  for (int i = t; i < NBIN; i += 256)       // fire-and-forget global atomics
    if (lhist[i]) atomicAdd(&ws->hist[b][i], lhist[i]);
  const unsigned int n = lcnt < CAP2S ? lcnt : CAP2S;
  if (t == 0) ws->cnt2c[b][chunk] = n;      // plain write, private slot
  for (unsigned int e = t; e < n; e += 256) ws->list2[b][chunk][e] = lcap[e];
}

// ---- K2: compact segments; top-8 of round-2; ranks -> (bin, residual)
__global__ __launch_bounds__(256) void k2_select(WS* __restrict__ ws) {
  const int b = blockIdx.x, t = threadIdx.x;
  const int lane = t & 63, wv = t >> 6;
  __shared__ unsigned long long lc[NSEG * CAP2S];
  __shared__ unsigned long long wmin[4];
  __shared__ unsigned int lbins[NBIN + 1];
  __shared__ unsigned int lq[NCLUST];
  __shared__ unsigned int psum[256];
  __shared__ unsigned int coff[NSEG + 1];
  if (t == 0) {                             // serial 32-prefix: trivial
    unsigned int run = 0;
    for (int c = 0; c < NSEG; ++c) {
      coff[c] = run;
      const unsigned int cc = ws->cnt2c[b][c];
      run += (cc < CAP2S ? cc : CAP2S);
    }
    coff[NSEG] = run;
  }
  __syncthreads();
  const int m2 = (int)coff[NSEG];
  for (int idx = t; idx < NSEG * CAP2S; idx += 256) {
    const int c = idx >> 6, e = idx & (CAP2S - 1);
    const unsigned int cc = ws->cnt2c[b][c];
    const unsigned int n = cc < CAP2S ? cc : CAP2S;
    if ((unsigned int)e < n) lc[coff[c] + e] = ws->list2[b][c][e];
  }
  __syncthreads();
  for (int j = 0; j < NCLUST; ++j) {
    unsigned long long lm = ~0ull;
    for (int e = t; e < m2; e += 256) lm = umin64(lm, lc[e]);
#pragma unroll
    for (int off = 32; off > 0; off >>= 1)
      lm = umin64(lm, __shfl_down(lm, off, 64));
    if (lane == 0) wmin[wv] = lm;
    __syncthreads();
    if (t == 0) {
      const unsigned long long M =
          umin64(umin64(wmin[0], wmin[1]), umin64(wmin[2], wmin[3]));
      wmin[0] = M;
      lq[j] = (unsigned int)(M & IDXMASK);
    }
    __syncthreads();
    const unsigned long long M = wmin[0];
    for (int e = t; e < m2; e += 256)
      if (lc[e] == M) lc[e] = ~0ull;
    __syncthreads();
  }
  unsigned int h[4];
  unsigned int s = 0;
  {
    const int base = t * 4;
#pragma unroll
    for (int r = 0; r < 4; ++r) { h[r] = ws->hist[b][base + r]; s += h[r]; }
    psum[t] = s;
  }
  __syncthreads();
  for (int st = 1; st < 256; st <<= 1) {
    unsigned int v = 0;
    if (t >= st) v = psum[t - st];
    __syncthreads();
    psum[t] += v;
    __syncthreads();
  }
  {
    unsigned int run = psum[t] - s;
    const int base = t * 4;
#pragma unroll
    for (int r = 0; r < 4; ++r) { lbins[base + r] = run; run += h[r]; }
    if (t == 255) lbins[NBIN] = run;   // == NPIX
  }
  __syncthreads();
  {
    const int base = t * 4;
#pragma unroll
    for (int r = 0; r < 4; ++r) {
      const unsigned int lo = lbins[base + r], hi = lbins[base + r + 1];
      for (int j = 0; j < NCLUST; ++j) {
        const unsigned int q = lq[j];
        if (q >= lo && q < hi) {
          ws->binr[b][j][0] = (unsigned int)(base + r);
          ws->binr[b][j][1] = q - lo;
        }
      }
    }
  }
}

// ---- K3a: bin-candidate capture from stored bits1 -> private segments
__global__ __launch_bounds__(256) void k3a_read(WS* __restrict__ ws) {
  const int b = blockIdx.x >> 5, chunk = blockIdx.x & 31, t = threadIdx.x;
  __shared__ unsigned long long lbuf[NCLUST][CAP1S];
  __shared__ unsigned int lcnt[NCLUST];
  if (t < NCLUST) lcnt[t] = 0u;
  __syncthreads();
  unsigned int bins[NCLUST];
#pragma unroll
  for (int j = 0; j < NCLUST; ++j) bins[j] = ws->binr[b][j][0];
  const unsigned int i0 = (unsigned int)chunk * 8192u;
  const uint4* __restrict__ p = (const uint4*)&ws->u.bits1[b][i0];
#pragma unroll 1
  for (int jj = 0; jj < 8; ++jj) {
    const uint4 v = p[jj * 256 + t];
    const unsigned int iv[4] = {v.x, v.y, v.z, v.w};
#pragma unroll
    for (int c = 0; c < 4; ++c) {
      const unsigned int bits1 = iv[c];
      const unsigned int i = i0 + (unsigned int)((jj * 256 + t) * 4 + c);
      const unsigned int bin = bits1 >> 22;
      const unsigned long long comp =
          ((unsigned long long)bits1 << 18) | (unsigned long long)i;
#pragma unroll
      for (int j = 0; j < NCLUST; ++j) {
        if (bin == bins[j]) {
          const unsigned int pos = atomicAdd(&lcnt[j], 1u);  // LDS atomic only
          if (pos < CAP1S) lbuf[j][pos] = comp;
        }
      }
    }
  }
  __syncthreads();
  if (t < NCLUST) {
    const unsigned int n = lcnt[t] < CAP1S ? lcnt[t] : CAP1S;
    ws->cnt1c[b][chunk][t] = n;            // plain write, private slot
  }
  __syncthreads();
  for (int idx = t; idx < NCLUST * CAP1S; idx += 256) {
    const int j = idx >> 5, e = idx & (CAP1S - 1);
    const unsigned int n = lcnt[j] < CAP1S ? lcnt[j] : CAP1S;
    if ((unsigned int)e < n) ws->list1[b][chunk][j][e] = lbuf[j][e];
  }
}

// ---- K4: compact per-chunk segments; in-bin rank selection -> centroid gather
__global__ __launch_bounds__(256) void k4_pick(const float* __restrict__ in,
                                               WS* __restrict__ ws) {
  const int b = blockIdx.x >> 3, j = blockIdx.x & 7, t = threadIdx.x;
  __shared__ unsigned long long l1[NSEG * CAP1S];
  __shared__ unsigned int coff[NSEG + 1];
  if (t == 0) {
    unsigned int run = 0;
    for (int c = 0; c < NSEG; ++c) {
      coff[c] = run;
      const unsigned int cc = ws->cnt1c[b][c][j];
      run += (cc < CAP1S ? cc : CAP1S);
    }
    coff[NSEG] = run;
  }
  __syncthreads();
  const int m = (int)coff[NSEG];
  for (int idx = t; idx < NSEG * CAP1S; idx += 256) {
    const int c = idx >> 5, e = idx & (CAP1S - 1);
    const unsigned int cc = ws->cnt1c[b][c][j];
    const unsigned int n = cc < CAP1S ? cc : CAP1S;
    if ((unsigned int)e < n) l1[coff[c] + e] = ws->list1[b][c][j][e];
  }
  __syncthreads();
  const unsigned int r = ws->binr[b][j][1];
  for (int e = t; e < m; e += 256) {
    const unsigned long long v = l1[e];
    unsigned int rank = 0;
    for (int f = 0; f < m; ++f) rank += (l1[f] < v) ? 1u : 0u;
    if (rank == r) {
      const unsigned int i = (unsigned int)(v & IDXMASK);
      const float* p = in + ((size_t)b * NPIX + i) * 3;
      ws->cent[0][b][j][0] = p[0];
      ws->cent[0][b][j][1] = p[1];
      ws->cent[0][b][j][2] = p[2];
    }
  }
}

// --------- assign. MODE 0: read f32 + pack-store u16 (iter 0, big ws)
//           MODE 1: read packed u16 (iters 1.., big ws)
//           MODE 2: read f32, no pack (all iters, small-ws fallback)
// All modes accumulate in u-space (x * 2^16; exact for MODE 0/2).
template <int MODE>
__global__ __launch_bounds__(256) void kmeans_assign(const float* __restrict__ in,
                                                     WS* __restrict__ ws,
                                                     int iter) {
  const int b = blockIdx.x >> 4, chunk = blockIdx.x & 15, t = threadIdx.x;
  __shared__ float scent[NCLUST][3];
  __shared__ float sred[4][NCLUST][4];

  // ---- phase A: this iteration's centroids (real space)
  if (iter == 0) {
    if (t < NCLUST * 3) (&scent[0][0])[t] = (&ws->cent[0][b][0][0])[t];
  } else {
    const int pb = (iter - 1) & 1;
    if (t < 32) {
      const int k = t >> 2, c = t & 3;
      float s = 0.f;
#pragma unroll
      for (int ch = 0; ch < NCHUNK; ++ch) s += ws->partial[pb][b][ch][k][c];
      sred[0][k][c] = s;
    }
    __syncthreads();
    if (t < NCLUST) {
      const int k = t;
      const float cnt = sred[0][k][3];
      const float denom = fmaxf(cnt, 1.f);
      float nx, ny, nz;
      if (cnt > 0.f) {
        nx = (sred[0][k][0] / denom) * UINV;   // u-space sum -> real mean
        ny = (sred[0][k][1] / denom) * UINV;
        nz = (sred[0][k][2] / denom) * UINV;
      } else {
        nx = ws->cent[iter - 1][b][k][0];
        ny = ws->cent[iter - 1][b][k][1];
        nz = ws->cent[iter - 1][b][k][2];
      }
      scent[k][0] = nx; scent[k][1] = ny; scent[k][2] = nz;
      ws->cent[iter][b][k][0] = nx;
      ws->cent[iter][b][k][1] = ny;
      ws->cent[iter][b][k][2] = nz;
    }
  }
  __syncthreads();

  float ca[NCLUST], cb[NCLUST], cc[NCLUST], cd[NCLUST];
#pragma unroll
  for (int k = 0; k < NCLUST; ++k) {
    const float sc = (MODE == 1) ? USCALE : 1.f;
    const float x = scent[k][0] * sc, y = scent[k][1] * sc, z = scent[k][2] * sc;
    ca[k] = -2.f * x; cb[k] = -2.f * y; cc[k] = -2.f * z;
    cd[k] = fmaf(x, x, fmaf(y, y, z * z));
  }
  float ax[NCLUST], ay[NCLUST], az[NCLUST], an[NCLUST];
#pragma unroll
  for (int k = 0; k < NCLUST; ++k) { ax[k] = 0.f; ay[k] = 0.f; az[k] = 0.f; an[k] = 0.f; }

  const size_t pixbase = (size_t)b * NPIX + (size_t)chunk * 16384;

  if (MODE == 1) {
    const uint4* __restrict__ pp = (const uint4*)(ws->u.packed + pixbase * 3);
#pragma unroll 2
    for (int jj = 0; jj < 8; ++jj) {
      const int g = jj * 256 + t;          // 8-pixel group
      const uint4 w0 = pp[g * 3], w1 = pp[g * 3 + 1], w2 = pp[g * 3 + 2];
      const unsigned int wrd[12] = {w0.x, w0.y, w0.z, w0.w, w1.x, w1.y,
                                    w1.z, w1.w, w2.x, w2.y, w2.z, w2.w};
#pragma unroll
      for (int p = 0; p < 8; ++p) {
        const int f = p * 3;
        const unsigned int c0 = (f & 1) ? (wrd[f >> 1] >> 16) : (wrd[f >> 1] & 0xFFFFu);
        const unsigned int c1 = ((f + 1) & 1) ? (wrd[(f + 1) >> 1] >> 16) : (wrd[(f + 1) >> 1] & 0xFFFFu);
        const unsigned int c2 = ((f + 2) & 1) ? (wrd[(f + 2) >> 1] >> 16) : (wrd[(f + 2) >> 1] & 0xFFFFu);
        const float x = (float)c0, y = (float)c1, z = (float)c2;
        float bv = fmaf(ca[0], x, fmaf(cb[0], y, fmaf(cc[0], z, cd[0])));
        int bk = 0;
#pragma unroll
        for (int k = 1; k < NCLUST; ++k) {
          const float tk = fmaf(ca[k], x, fmaf(cb[k], y, fmaf(cc[k], z, cd[k])));
          if (tk < bv) { bv = tk; bk = k; }
        }
#pragma unroll
        for (int k = 0; k < NCLUST; ++k) {
          const float w = (bk == k) ? 1.f : 0.f;
          ax[k] = fmaf(w, x, ax[k]);
          ay[k] = fmaf(w, y, ay[k]);
          az[k] = fmaf(w, z, az[k]);
          an[k] += w;
        }
      }
    }
  } else {
    const float4* __restrict__ in4 = (const float4*)(in + pixbase * 3);
    uint2* __restrict__ pk =
        (MODE == 0) ? (uint2*)(ws->u.packed + pixbase * 3) : (uint2*)0;
#pragma unroll 4
    for (int jj = 0; jj < 16; ++jj) {
      const int g = jj * 256 + t;          // 4-pixel group
      const int fb = g * 3;
      const float4 v0 = in4[fb], v1 = in4[fb + 1], v2 = in4[fb + 2];
      float pxv[12];
      pxv[0] = v0.x;  pxv[1] = v0.y;  pxv[2]  = v0.z;  pxv[3]  = v0.w;
      pxv[4] = v1.x;  pxv[5] = v1.y;  pxv[6]  = v1.z;  pxv[7]  = v1.w;
      pxv[8] = v2.x;  pxv[9] = v2.y;  pxv[10] = v2.z;  pxv[11] = v2.w;
      if (MODE == 0) {
        unsigned int uq[12];
#pragma unroll
        for (int c = 0; c < 12; ++c) {
          unsigned int u = (unsigned int)fmaf(pxv[c], USCALE, 0.5f);
          uq[c] = u > 65535u ? 65535u : u;
        }
        pk[fb]     = make_uint2(uq[0] | (uq[1] << 16), uq[2] | (uq[3] << 16));
        pk[fb + 1] = make_uint2(uq[4] | (uq[5] << 16), uq[6] | (uq[7] << 16));
        pk[fb + 2] = make_uint2(uq[8] | (uq[9] << 16), uq[10] | (uq[11] << 16));
      }
#pragma unroll
      for (int p = 0; p < 4; ++p) {
        const float x = pxv[p * 3], y = pxv[p * 3 + 1], z = pxv[p * 3 + 2];
        float bv = fmaf(ca[0], x, fmaf(cb[0], y, fmaf(cc[0], z, cd[0])));
        int bk = 0;
#pragma unroll
        for (int k = 1; k < NCLUST; ++k) {
          const float tk = fmaf(ca[k], x, fmaf(cb[k], y, fmaf(cc[k], z, cd[k])));
          if (tk < bv) { bv = tk; bk = k; }
        }
        const float xs = x * USCALE, ys = y * USCALE, zs = z * USCALE;  // exact
#pragma unroll
        for (int k = 0; k < NCLUST; ++k) {
          const float w = (bk == k) ? 1.f : 0.f;
          ax[k] = fmaf(w, xs, ax[k]);
          ay[k] = fmaf(w, ys, ay[k]);
          az[k] = fmaf(w, zs, az[k]);
          an[k] += w;
        }
      }
    }
  }

  // ---- block reduction -> private partial slot (u-space)
  const int lane = t & 63, wv = t >> 6;
#pragma unroll
  for (int k = 0; k < NCLUST; ++k) {
    float vx = ax[k], vy = ay[k], vz = az[k], vn = an[k];
#pragma unroll
    for (int off = 32; off > 0; off >>= 1) {
      vx += __shfl_down(vx, off, 64);
      vy += __shfl_down(vy, off, 64);
      vz += __shfl_down(vz, off, 64);
      vn += __shfl_down(vn, off, 64);
    }
    if (lane == 0) {
      sred[wv][k][0] = vx; sred[wv][k][1] = vy;
      sred[wv][k][2] = vz; sred[wv][k][3] = vn;
    }
  }
  __syncthreads();
  if (t < 32) {
    const int k = t >> 2, c = t & 3;
    const float p = sred[0][k][c] + sred[1][k][c] + sred[2][k][c] + sred[3][k][c];
    ws->partial[iter & 1][b][chunk][k][c] = p;
  }
}

// ----------------------- final: C_10 from iter-9 partials -> output
__global__ __launch_bounds__(64) void kfinal(WS* __restrict__ ws,
                                             float* __restrict__ out) {
  const int b = blockIdx.x, t = threadIdx.x;
  __shared__ float s[NCLUST][4];
  if (t < 32) {
    const int k = t >> 2, c = t & 3;
    float v = 0.f;
#pragma unroll
    for (int ch = 0; ch < NCHUNK; ++ch)
      v += ws->partial[(NITER - 1) & 1][b][ch][k][c];
    s[k][c] = v;
  }
  __syncthreads();
  if (t < NCLUST) {
    const int k = t;
    const float cnt = s[k][3];
    const float denom = fmaxf(cnt, 1.f);
    float nx, ny, nz;
    if (cnt > 0.f) {
      nx = (s[k][0] / denom) * UINV;
      ny = (s[k][1] / denom) * UINV;
      nz = (s[k][2] / denom) * UINV;
    } else {
      nx = ws->cent[NITER - 1][b][k][0];
      ny = ws->cent[NITER - 1][b][k][1];
      nz = ws->cent[NITER - 1][b][k][2];
    }
    const int o = (b * NCLUST + k) * 3;
    out[o + 0] = nx; out[o + 1] = ny; out[o + 2] = nz;
  }
}

extern "C" void kernel_launch(void* const* d_in, const int* in_sizes, int n_in,
                              void* d_out, int out_size, void* d_ws, size_t ws_size,
                              hipStream_t stream) {
  const float* in = (const float*)d_in[0];
  float* out = (float*)d_out;
  WS* ws = (WS*)d_ws;   // ~110 MB full; union tail only needs bits1 otherwise
  const bool packed_ok = ws_size >= sizeof(WS);   // deterministic: graph-safe

  k0_setup<<<NBATCH, 256, 0, stream>>>(in, ws);
  k1_scan<<<NBATCH * NSEG, 256, 0, stream>>>(ws);
  k2_select<<<NBATCH, 256, 0, stream>>>(ws);
  k3a_read<<<NBATCH * NSEG, 256, 0, stream>>>(ws);
  k4_pick<<<NBATCH * NCLUST, 256, 0, stream>>>(in, ws);
  if (packed_ok) {
    kmeans_assign<0><<<NBATCH * NCHUNK, 256, 0, stream>>>(in, ws, 0);
    for (int it = 1; it < NITER; ++it)
      kmeans_assign<1><<<NBATCH * NCHUNK, 256, 0, stream>>>(in, ws, it);
  } else {
    for (int it = 0; it < NITER; ++it)
      kmeans_assign<2><<<NBATCH * NCHUNK, 256, 0, stream>>>(in, ws, it);
  }
  kfinal<<<NBATCH, 64, 0, stream>>>(ws, out);
}